// Round 11
// baseline (417.269 us; speedup 1.0000x reference)
//
#include <hip/hip_runtime.h>
#include <hip/hip_bf16.h>

// Problem constants (from reference)
#define TT 128   // time points
#define DD 64    // state dim
#define HH 256   // f-net hidden
#define HK 128   // kernel-net hidden
#define JH (TT*HK)      // 16384 contraction dim
#define HD (HK*DD)      // 8192
#define NCHUNK 64       // jh chunks of 256 (= 2 j's each)

// ---------------------------------------------------------------------------
// k_FM2: one block per row j (128 blocks, 256 threads).
//  1) y_j = z0 + dt*trap(G[0..j])  (z0 if it==0)        [r9 k_F, proven]
//  2) MLP: F_j = tanh(y@W1+b1)@W2+b2 -> fs in LDS (never hits global)
//  3) bF[j,d] = sum_e bk2[d*DD+e]*fs[e]
//  4) M row j: M[j,hd] = sum_e fs[e]*Wk2[h, d*DD+e]  (hd = h*64+d)
//     — no redundancy: row j's M depends only on fs. e-loop fully unrolled
//     so all 16 float4 Wk2 loads per chunk are in flight together.
// ---------------------------------------------------------------------------
__global__ void __launch_bounds__(256)
k_FM2(const float* __restrict__ G, const float* __restrict__ z0,
      const float* __restrict__ t,
      const float* __restrict__ W1, const float* __restrict__ b1,
      const float* __restrict__ W2, const float* __restrict__ b2,
      const float* __restrict__ bk2, const float* __restrict__ Wk2,
      float* __restrict__ M, float* __restrict__ bF, int it) {
    int j = blockIdx.x, tid = threadIdx.x;
    int part = tid >> 6, d = tid & 63;
    __shared__ float red[4][64];
    __shared__ float ys[DD];
    __shared__ float hs[HH];
    __shared__ float fs[DD];
    float dt = t[1] - t[0];

    // ---- 1) y ----
    if (it == 0) {
        if (tid < DD) ys[tid] = z0[tid];
    } else {
        float s = 0.f;
        if (j > 0) {
            for (int jp = part; jp <= j; jp += 4) {
                float w = (jp == 0 || jp == j) ? 0.5f : 1.0f;
                s += w * G[jp * DD + d];
            }
        }
        red[part][d] = s;
        __syncthreads();
        if (part == 0)
            ys[d] = z0[d] + dt * (red[0][d] + red[1][d] + red[2][d] + red[3][d]);
    }
    __syncthreads();

    // ---- 2) MLP ----
    float acc = b1[tid];
    #pragma unroll 8
    for (int e = 0; e < DD; ++e) acc += ys[e] * W1[e * HH + tid];
    hs[tid] = tanhf(acc);
    __syncthreads();
    {
        float s = 0.f;
        #pragma unroll 8
        for (int h = part * 64; h < part * 64 + 64; ++h) s += hs[h] * W2[h * DD + d];
        red[part][d] = s;
    }
    __syncthreads();
    if (part == 0)
        fs[d] = b2[d] + red[0][d] + red[1][d] + red[2][d] + red[3][d];
    __syncthreads();

    // ---- 3) bF ----
    {
        float s = 0.f;
        #pragma unroll
        for (int e = part * 16; e < part * 16 + 16; ++e) s += bk2[d * DD + e] * fs[e];
        red[part][d] = s;
    }
    __syncthreads();
    if (part == 0)
        bF[j * DD + d] = red[0][d] + red[1][d] + red[2][d] + red[3][d];

    // ---- 4) M row j ----
    // local copy of fs into registers as float4s for the MAC loop
    float4 f0 = *(const float4*)&fs[0];
    // (read via LDS below; fs stays resident)
    (void)f0;
    #pragma unroll 4
    for (int c = 0; c < 32; ++c) {
        int hd = c * 256 + tid;
        const float* Wrow = Wk2 + (size_t)(hd >> 6) * (DD * DD) + (size_t)(hd & 63) * DD;
        float a = 0.f;
        #pragma unroll
        for (int e = 0; e < DD; e += 8) {
            float4 wa = *(const float4*)(Wrow + e);
            float4 wb = *(const float4*)(Wrow + e + 4);
            float4 fa = *(const float4*)&fs[e];
            float4 fb = *(const float4*)&fs[e + 4];
            a += fa.x*wa.x + fa.y*wa.y + fa.z*wa.z + fa.w*wa.w
               + fb.x*wb.x + fb.y*wb.y + fb.z*wb.z + fb.w*wb.w;
        }
        M[(size_t)j * HD + hd] = a;
    }
}

// ---------------------------------------------------------------------------
// k_G1 (r9-proven): P[c,i,d] = sum_{jh in chunk c (256 wide)} A[i,jh]*M[jh,d]
// grid: (16 itiles of 8 rows, 64 chunks); active iff c <= 4*itile+3 (544 blocks).
// A computed on the fly (8 tanh/thread). Final iteration: block (0,0) seeds
// out = z0 (consumed by k_Gfin's atomics after the launch boundary).
// ---------------------------------------------------------------------------
__global__ void __launch_bounds__(256)
k_G1(const float* __restrict__ t, const float* __restrict__ Wk1,
     const float* __restrict__ bk1, const float* __restrict__ M,
     float* __restrict__ P, const float* __restrict__ z0,
     float* __restrict__ out, int final_it) {
    int itile = blockIdx.x, c = blockIdx.y;
    if (c > 4 * itile + 3) return;
    __shared__ __attribute__((aligned(16))) float As[8 * 256];   // 8 KB
    __shared__ float red[4][8][64];                              // 8 KB
    int tid = threadIdx.x, sub = tid >> 6, d = tid & 63;

    {
        float dt = t[1] - t[0];
        int h = tid & 127;
        int j = 2 * c + (tid >> 7);
        float wk0 = Wk1[h], wk1v = Wk1[HK + h], bk = bk1[h];
        float tj = t[j];
        #pragma unroll
        for (int k = 0; k < 8; ++k) {
            int i = itile * 8 + k;
            float w = (i == 0 || j > i) ? 0.f : dt * ((j == 0 || j == i) ? 0.5f : 1.0f);
            As[k * 256 + tid] = w * tanhf(t[i] * wk0 + tj * wk1v + bk);
        }
    }
    if (final_it && itile == 0 && c == 0 && tid < DD) out[tid] = z0[tid];
    __syncthreads();

    float acc[8] = {0.f,0.f,0.f,0.f,0.f,0.f,0.f,0.f};
    const float* Mp = M + ((size_t)c * 256) * DD + d;
    int jl0 = sub * 64;
    for (int jl = jl0; jl < jl0 + 64; jl += 8) {
        float m0 = Mp[(size_t)(jl + 0) * DD];
        float m1 = Mp[(size_t)(jl + 1) * DD];
        float m2 = Mp[(size_t)(jl + 2) * DD];
        float m3 = Mp[(size_t)(jl + 3) * DD];
        float m4 = Mp[(size_t)(jl + 4) * DD];
        float m5 = Mp[(size_t)(jl + 5) * DD];
        float m6 = Mp[(size_t)(jl + 6) * DD];
        float m7 = Mp[(size_t)(jl + 7) * DD];
        #pragma unroll
        for (int r = 0; r < 8; ++r) {
            float4 a0 = *(const float4*)&As[r * 256 + jl];
            float4 a1 = *(const float4*)&As[r * 256 + jl + 4];
            acc[r] += a0.x*m0 + a0.y*m1 + a0.z*m2 + a0.w*m3
                    + a1.x*m4 + a1.y*m5 + a1.z*m6 + a1.w*m7;
        }
    }
    #pragma unroll
    for (int r = 0; r < 8; ++r) red[sub][r][d] = acc[r];
    __syncthreads();
    if (sub == 0) {
        #pragma unroll
        for (int r = 0; r < 8; ++r) {
            float v = red[0][r][d] + red[1][r][d] + red[2][r][d] + red[3][r][d];
            P[(size_t)c * (TT * DD) + (itile * 8 + r) * DD + d] = v;
        }
    }
}

// ---------------------------------------------------------------------------
// k_Gfin (r9-proven): G[j,d] = sum_{c<=j>>1} P[c,j,d] + dt*trap(bF[0..j], d).
// Final iteration: also atomicAdd dt*w_j*G[j,d] into out (pre-seeded = z0 by
// the final k_G1) — 8K atomics over 64 addresses (~2 us).
// ---------------------------------------------------------------------------
__global__ void __launch_bounds__(256)
k_Gfin(const float* __restrict__ P, const float* __restrict__ bF,
       const float* __restrict__ t, float* __restrict__ G,
       float* __restrict__ out, int final_it) {
    int j = blockIdx.x, tid = threadIdx.x;
    int part = tid >> 6, d = tid & 63;
    __shared__ float red[4][64];
    float dt = t[1] - t[0];
    float a = 0.f;
    int cmax = j >> 1;
    for (int c = part; c <= cmax; c += 4) a += P[(size_t)c * (TT * DD) + j * DD + d];
    if (j > 0) {
        float s = 0.f;
        for (int jp = part; jp <= j; jp += 4) {
            float w = (jp == 0 || jp == j) ? 0.5f : 1.0f;
            s += w * bF[jp * DD + d];
        }
        a += dt * s;
    }
    red[part][d] = a;
    __syncthreads();
    if (part == 0) {
        float v = red[0][d] + red[1][d] + red[2][d] + red[3][d];
        G[j * DD + d] = v;
        if (final_it) {
            float wj = (j == 0 || j == TT - 1) ? 0.5f : 1.0f;
            atomicAdd(&out[d], dt * wj * v);
        }
    }
}

extern "C" void kernel_launch(void* const* d_in, const int* in_sizes, int n_in,
                              void* d_out, int out_size, void* d_ws, size_t ws_size,
                              hipStream_t stream) {
    const float* z0  = (const float*)d_in[0];
    const float* t   = (const float*)d_in[1];
    const float* W1  = (const float*)d_in[2];
    const float* b1  = (const float*)d_in[3];
    const float* W2  = (const float*)d_in[4];
    const float* b2  = (const float*)d_in[5];
    const float* Wk1 = (const float*)d_in[6];
    const float* bk1 = (const float*)d_in[7];
    const float* Wk2 = (const float*)d_in[8];
    const float* bk2 = (const float*)d_in[9];
    float* out = (float*)d_out;

    float* ws = (float*)d_ws;
    float* M  = ws;                        // T*HK*D     = 1,048,576
    float* bF = M  + (size_t)TT*HK*DD;     // T*D
    float* G  = bF + TT*DD;                // T*D
    float* P  = G  + TT*DD;                // NCHUNK*T*D = 524,288

    // 9 launches: 3 x (FM2, G1, Gfin); output folded into the final pair.
    for (int it = 0; it < 3; ++it) {
        int fin = (it == 2) ? 1 : 0;
        k_FM2<<<TT, 256, 0, stream>>>(G, z0, t, W1, b1, W2, b2, bk2, Wk2,
                                      M, bF, it);
        k_G1<<<dim3(16, NCHUNK), 256, 0, stream>>>(t, Wk1, bk1, M, P, z0, out, fin);
        k_Gfin<<<TT, 256, 0, stream>>>(P, bF, t, G, out, fin);
    }
}

// Round 12
// 185.699 us; speedup vs baseline: 2.2470x; 2.2470x over previous
//
#include <hip/hip_runtime.h>
#include <hip/hip_bf16.h>

// Problem constants (from reference)
#define TT 128   // time points
#define DD 64    // state dim
#define HH 256   // f-net hidden
#define HK 128   // kernel-net hidden
#define JH (TT*HK)      // 16384 contraction dim
#define HD (HK*DD)      // 8192
#define NCHUNK 64       // jh chunks of 256 (= 2 j's each)

// ---------------------------------------------------------------------------
// k_F0M0 (it0 degeneracy): y_j == z0 for all j, so F/bF/M rows are identical.
// 32 blocks: each redundantly runs the single-row MLP (f(z0)), then writes its
// 256-entry slice of M0[HD]. Block 0 also writes bF0[DD].
// ---------------------------------------------------------------------------
__global__ void __launch_bounds__(256)
k_F0M0(const float* __restrict__ z0,
       const float* __restrict__ W1, const float* __restrict__ b1,
       const float* __restrict__ W2, const float* __restrict__ b2,
       const float* __restrict__ bk2, const float* __restrict__ Wk2,
       float* __restrict__ M0, float* __restrict__ bF0) {
    int bx = blockIdx.x, tid = threadIdx.x;
    int part = tid >> 6, d = tid & 63;
    __shared__ float red[4][64];
    __shared__ float ys[DD];
    __shared__ float hs[HH];
    __shared__ __attribute__((aligned(16))) float fs[DD];
    if (tid < DD) ys[tid] = z0[tid];
    __syncthreads();
    float acc = b1[tid];
    #pragma unroll 8
    for (int e = 0; e < DD; ++e) acc += ys[e] * W1[e * HH + tid];
    hs[tid] = tanhf(acc);
    __syncthreads();
    {
        float s = 0.f;
        #pragma unroll 8
        for (int h = part * 64; h < part * 64 + 64; ++h) s += hs[h] * W2[h * DD + d];
        red[part][d] = s;
    }
    __syncthreads();
    if (part == 0)
        fs[d] = b2[d] + red[0][d] + red[1][d] + red[2][d] + red[3][d];
    __syncthreads();
    if (bx == 0) {
        float s = 0.f;
        #pragma unroll
        for (int e = part * 16; e < part * 16 + 16; ++e) s += bk2[d * DD + e] * fs[e];
        red[part][d] = s;
        __syncthreads();
        if (part == 0)
            bF0[d] = red[0][d] + red[1][d] + red[2][d] + red[3][d];
    }
    // M0 slice
    int hd = bx * 256 + tid;
    const float* Wrow = Wk2 + (size_t)(hd >> 6) * (DD * DD) + (size_t)(hd & 63) * DD;
    float a = 0.f;
    #pragma unroll
    for (int e = 0; e < DD; e += 8) {
        float4 wa = *(const float4*)(Wrow + e);
        float4 wb = *(const float4*)(Wrow + e + 4);
        float4 fa = *(const float4*)&fs[e];
        float4 fb = *(const float4*)&fs[e + 4];
        a += fa.x*wa.x + fa.y*wa.y + fa.z*wa.z + fa.w*wa.w
           + fb.x*wb.x + fb.y*wb.y + fb.z*wb.z + fb.w*wb.w;
    }
    M0[hd] = a;
}

// ---------------------------------------------------------------------------
// k_G0 (it0 degeneracy): with M j-constant,
//   G_i[d] = sum_h B[i,h]*M0[h*64+d] + dt*i*bF0[d],   B[i,h]=sum_{j<=i} w_ij*hK
// One block per row i. Stage 1: B row (threads = 2 j-halves x 128 h, <=64
// tanh/thread). Stage 2: 32-h slices per part, LDS reduce. G[0] = 0 exactly.
// ---------------------------------------------------------------------------
__global__ void __launch_bounds__(256)
k_G0(const float* __restrict__ t, const float* __restrict__ Wk1,
     const float* __restrict__ bk1, const float* __restrict__ M0,
     const float* __restrict__ bF0, float* __restrict__ G) {
    int i = blockIdx.x, tid = threadIdx.x;
    int part = tid >> 6, d = tid & 63;
    __shared__ float Bpart[2][HK];
    __shared__ float Bs[HK];
    __shared__ float red[4][64];
    float dt = t[1] - t[0];
    int h = tid & 127, half = tid >> 7;
    float b = 0.f;
    if (i > 0) {
        float wk0 = Wk1[h], wk1v = Wk1[HK + h], bk = bk1[h];
        float ti = t[i];
        for (int j = half; j <= i; j += 2) {
            float w = dt * ((j == 0 || j == i) ? 0.5f : 1.0f);
            b += w * tanhf(ti * wk0 + t[j] * wk1v + bk);
        }
    }
    Bpart[half][h] = b;
    __syncthreads();
    if (tid < HK) Bs[tid] = Bpart[0][tid] + Bpart[1][tid];
    __syncthreads();
    float a = 0.f;
    #pragma unroll 8
    for (int h2 = part * 32; h2 < part * 32 + 32; ++h2)
        a += Bs[h2] * M0[h2 * DD + d];
    red[part][d] = a;
    __syncthreads();
    if (part == 0) {
        float g = red[0][d] + red[1][d] + red[2][d] + red[3][d];
        if (i > 0) g += dt * (float)i * bF0[d];   // sum_{j<=i} w_ij = dt*i
        G[i * DD + d] = g;
    }
}

// ---------------------------------------------------------------------------
// k_F (r9-proven): block j: y_j = z0 + dt*trap(G[0..j]), then
// F[j] = tanh(y@W1+b1)@W2+b2, bF[j,d] = sum_e bk2[d*DD+e]*F[j,e]
// ---------------------------------------------------------------------------
__global__ void __launch_bounds__(256)
k_F(const float* __restrict__ G, const float* __restrict__ z0,
    const float* __restrict__ t,
    const float* __restrict__ W1, const float* __restrict__ b1,
    const float* __restrict__ W2, const float* __restrict__ b2,
    const float* __restrict__ bk2,
    float* __restrict__ F, float* __restrict__ bF) {
    int j = blockIdx.x, tid = threadIdx.x;
    int part = tid >> 6, d = tid & 63;
    __shared__ float red[4][64];
    __shared__ float ys[DD];
    __shared__ float hs[HH];
    __shared__ float fs[DD];
    float dt = t[1] - t[0];
    {
        float s = 0.f;
        if (j > 0) {
            for (int jp = part; jp <= j; jp += 4) {
                float w = (jp == 0 || jp == j) ? 0.5f : 1.0f;
                s += w * G[jp * DD + d];
            }
        }
        red[part][d] = s;
        __syncthreads();
        if (part == 0)
            ys[d] = z0[d] + dt * (red[0][d] + red[1][d] + red[2][d] + red[3][d]);
    }
    __syncthreads();
    float acc = b1[tid];
    #pragma unroll 8
    for (int e = 0; e < DD; ++e) acc += ys[e] * W1[e * HH + tid];
    hs[tid] = tanhf(acc);
    __syncthreads();
    {
        float s = 0.f;
        #pragma unroll 8
        for (int h = part * 64; h < part * 64 + 64; ++h) s += hs[h] * W2[h * DD + d];
        red[part][d] = s;
    }
    __syncthreads();
    if (part == 0) {
        float a = b2[d] + red[0][d] + red[1][d] + red[2][d] + red[3][d];
        fs[d] = a;
        F[j * DD + d] = a;
    }
    __syncthreads();
    {
        float s = 0.f;
        #pragma unroll
        for (int e = part * 16; e < part * 16 + 16; ++e) s += bk2[d * DD + e] * fs[e];
        red[part][d] = s;
    }
    __syncthreads();
    if (part == 0)
        bF[j * DD + d] = red[0][d] + red[1][d] + red[2][d] + red[3][d];
}

// ---------------------------------------------------------------------------
// k_M (r9-proven): M[j*HD + hd] = sum_e F[j,e] * Wk2[h, d*DD + e]
// grid: (32 hd-chunks of 256, 16 j-chunks of 8) — 8-way Wk2 amortization.
// ---------------------------------------------------------------------------
__global__ void __launch_bounds__(256)
k_M(const float* __restrict__ F, const float* __restrict__ Wk2,
    float* __restrict__ M) {
    int tid = threadIdx.x;
    int hd = blockIdx.x * 256 + tid;
    int j0 = blockIdx.y * 8;
    __shared__ __attribute__((aligned(16))) float Fs[8][64];
    for (int k = tid; k < 8 * DD; k += 256) Fs[k >> 6][k & 63] = F[j0 * DD + k];
    __syncthreads();
    float acc[8] = {0.f,0.f,0.f,0.f,0.f,0.f,0.f,0.f};
    const float* Wrow = Wk2 + (size_t)(hd >> 6) * (DD * DD) + (size_t)(hd & 63) * DD;
    for (int e = 0; e < DD; e += 8) {
        float4 wa = *(const float4*)(Wrow + e);
        float4 wb = *(const float4*)(Wrow + e + 4);
        #pragma unroll
        for (int r = 0; r < 8; ++r) {
            float4 f0 = *(const float4*)&Fs[r][e];
            float4 f1 = *(const float4*)&Fs[r][e + 4];
            acc[r] += f0.x*wa.x + f0.y*wa.y + f0.z*wa.z + f0.w*wa.w
                    + f1.x*wb.x + f1.y*wb.y + f1.z*wb.z + f1.w*wb.w;
        }
    }
    #pragma unroll
    for (int r = 0; r < 8; ++r) M[(size_t)(j0 + r) * HD + hd] = acc[r];
}

// ---------------------------------------------------------------------------
// k_G1 (r9-proven): P[c,i,d] = sum_{jh in chunk c (256 wide)} A[i,jh]*M[jh,d]
// grid: (16 itiles of 8 rows, 64 chunks); active iff c <= 4*itile+3 (544 blocks).
// A computed on the fly. Final iteration: block (0,0) seeds out = z0.
// ---------------------------------------------------------------------------
__global__ void __launch_bounds__(256)
k_G1(const float* __restrict__ t, const float* __restrict__ Wk1,
     const float* __restrict__ bk1, const float* __restrict__ M,
     float* __restrict__ P, const float* __restrict__ z0,
     float* __restrict__ out, int final_it) {
    int itile = blockIdx.x, c = blockIdx.y;
    if (c > 4 * itile + 3) return;
    __shared__ __attribute__((aligned(16))) float As[8 * 256];   // 8 KB
    __shared__ float red[4][8][64];                              // 8 KB
    int tid = threadIdx.x, sub = tid >> 6, d = tid & 63;

    {
        float dt = t[1] - t[0];
        int h = tid & 127;
        int j = 2 * c + (tid >> 7);
        float wk0 = Wk1[h], wk1v = Wk1[HK + h], bk = bk1[h];
        float tj = t[j];
        #pragma unroll
        for (int k = 0; k < 8; ++k) {
            int i = itile * 8 + k;
            float w = (i == 0 || j > i) ? 0.f : dt * ((j == 0 || j == i) ? 0.5f : 1.0f);
            As[k * 256 + tid] = w * tanhf(t[i] * wk0 + tj * wk1v + bk);
        }
    }
    if (final_it && itile == 0 && c == 0 && tid < DD) out[tid] = z0[tid];
    __syncthreads();

    float acc[8] = {0.f,0.f,0.f,0.f,0.f,0.f,0.f,0.f};
    const float* Mp = M + ((size_t)c * 256) * DD + d;
    int jl0 = sub * 64;
    for (int jl = jl0; jl < jl0 + 64; jl += 8) {
        float m0 = Mp[(size_t)(jl + 0) * DD];
        float m1 = Mp[(size_t)(jl + 1) * DD];
        float m2 = Mp[(size_t)(jl + 2) * DD];
        float m3 = Mp[(size_t)(jl + 3) * DD];
        float m4 = Mp[(size_t)(jl + 4) * DD];
        float m5 = Mp[(size_t)(jl + 5) * DD];
        float m6 = Mp[(size_t)(jl + 6) * DD];
        float m7 = Mp[(size_t)(jl + 7) * DD];
        #pragma unroll
        for (int r = 0; r < 8; ++r) {
            float4 a0 = *(const float4*)&As[r * 256 + jl];
            float4 a1 = *(const float4*)&As[r * 256 + jl + 4];
            acc[r] += a0.x*m0 + a0.y*m1 + a0.z*m2 + a0.w*m3
                    + a1.x*m4 + a1.y*m5 + a1.z*m6 + a1.w*m7;
        }
    }
    #pragma unroll
    for (int r = 0; r < 8; ++r) red[sub][r][d] = acc[r];
    __syncthreads();
    if (sub == 0) {
        #pragma unroll
        for (int r = 0; r < 8; ++r) {
            float v = red[0][r][d] + red[1][r][d] + red[2][r][d] + red[3][r][d];
            P[(size_t)c * (TT * DD) + (itile * 8 + r) * DD + d] = v;
        }
    }
}

// ---------------------------------------------------------------------------
// k_Gfin (r9-proven): G[j,d] = sum_{c<=j>>1} P[c,j,d] + dt*trap(bF[0..j], d).
// Final iteration: also atomicAdd dt*w_j*G[j,d] into out (pre-seeded = z0).
// ---------------------------------------------------------------------------
__global__ void __launch_bounds__(256)
k_Gfin(const float* __restrict__ P, const float* __restrict__ bF,
       const float* __restrict__ t, float* __restrict__ G,
       float* __restrict__ out, int final_it) {
    int j = blockIdx.x, tid = threadIdx.x;
    int part = tid >> 6, d = tid & 63;
    __shared__ float red[4][64];
    float dt = t[1] - t[0];
    float a = 0.f;
    int cmax = j >> 1;
    for (int c = part; c <= cmax; c += 4) a += P[(size_t)c * (TT * DD) + j * DD + d];
    if (j > 0) {
        float s = 0.f;
        for (int jp = part; jp <= j; jp += 4) {
            float w = (jp == 0 || jp == j) ? 0.5f : 1.0f;
            s += w * bF[jp * DD + d];
        }
        a += dt * s;
    }
    red[part][d] = a;
    __syncthreads();
    if (part == 0) {
        float v = red[0][d] + red[1][d] + red[2][d] + red[3][d];
        G[j * DD + d] = v;
        if (final_it) {
            float wj = (j == 0 || j == TT - 1) ? 0.5f : 1.0f;
            atomicAdd(&out[d], dt * wj * v);
        }
    }
}

extern "C" void kernel_launch(void* const* d_in, const int* in_sizes, int n_in,
                              void* d_out, int out_size, void* d_ws, size_t ws_size,
                              hipStream_t stream) {
    const float* z0  = (const float*)d_in[0];
    const float* t   = (const float*)d_in[1];
    const float* W1  = (const float*)d_in[2];
    const float* b1  = (const float*)d_in[3];
    const float* W2  = (const float*)d_in[4];
    const float* b2  = (const float*)d_in[5];
    const float* Wk1 = (const float*)d_in[6];
    const float* bk1 = (const float*)d_in[7];
    const float* Wk2 = (const float*)d_in[8];
    const float* bk2 = (const float*)d_in[9];
    float* out = (float*)d_out;

    float* ws  = (float*)d_ws;
    float* M   = ws;                        // T*HK*D     = 1,048,576
    float* F   = M   + (size_t)TT*HK*DD;    // T*D
    float* bF  = F   + TT*DD;               // T*D
    float* G   = bF  + TT*DD;               // T*D
    float* P   = G   + TT*DD;               // NCHUNK*T*D = 524,288
    float* M0  = P   + (size_t)NCHUNK*TT*DD;// HD = 8192
    float* bF0 = M0  + HD;                  // DD

    // 10 launches:
    // it0 (degenerate: y == z0 for all rows) — 2 launches
    k_F0M0<<<32, 256, 0, stream>>>(z0, W1, b1, W2, b2, bk2, Wk2, M0, bF0);
    k_G0<<<TT, 256, 0, stream>>>(t, Wk1, bk1, M0, bF0, G);
    // it1, it2 — 4 launches each (r9-proven kernels)
    for (int it = 1; it < 3; ++it) {
        int fin = (it == 2) ? 1 : 0;
        k_F<<<TT, 256, 0, stream>>>(G, z0, t, W1, b1, W2, b2, bk2, F, bF);
        k_M<<<dim3(32, 16), 256, 0, stream>>>(F, Wk2, M);
        k_G1<<<dim3(16, NCHUNK), 256, 0, stream>>>(t, Wk1, bk1, M, P, z0, out, fin);
        k_Gfin<<<TT, 256, 0, stream>>>(P, bF, t, G, out, fin);
    }
}